// Round 9
// baseline (184.777 us; speedup 1.0000x reference)
//
#include <hip/hip_runtime.h>
#include <math.h>

// Problem constants
#define BATCH 256
#define IC    1152   // 32*6*6 input capsule positions
#define DD    8
#define OO    10
#define EE    16
#define BTILE 64     // batches per block (one wave per o, lanes = batch)
#define NBT   4      // BATCH / BTILE
#define NT    640    // OO * BTILE threads per block (10 waves)
#define CHUNK 8      // ijk positions per block (fits 64 KB LDS with W staged)
#define NCHUNK 144   // IC / CHUNK
#define WPC   (OO * DD * EE)   // 1280 floats of W per ijk

// pass kernel: W served from LDS broadcast instead of the scalar pipe.
// Evidence r0-r8: every s_load-W variant = 43-64 us/pass (SGPR_Count=32 ->
// 1 x16 in flight; per-CU K$ miss queue serializes ~200-250cyc each),
// invariant to barriers/occupancy/sweeps. VALU floor ~5.5 us. r4 ruled out
// divergent VMEM W; r7 ruled out uniform VMEM at 32 VGPR. This round: stage
// the W chunk into LDS cooperatively (coalesced float4, vmcnt-pipelined),
// then wave-uniform ds_read_b128 broadcasts (conflict-free per m136,
// lgkm-pipelined, results in VGPRs). LDS cost ~4-8 us/CU/pass.
//  - CHUNK=8: LDS = W 40K + x 16K + elg 5K = 61 KB < 64 KB static limit.
//  - single W sweep, u[16] across ONE barrier per ijk (r8 structure).
//  - exp-before-barrier softmax, no max-sub (logits bounded, proven r1-r8).
//  - NO launch_bounds cap (r1/r3: caps -> catastrophic spills).
//  Checks: LDS 62464 B, VGPR 64-80, WRITE_SIZE ~23.7 MB (no spill),
//  SQ_LDS_BANK_CONFLICT ~0.
__global__ __launch_bounds__(NT) void caps_pass_kernel(
    const float* __restrict__ x,       // [256][1152][8]
    const float* __restrict__ W,       // [1152][10][8][16]
    const float* __restrict__ V,       // [256][10][16] accumulated v
    float* __restrict__ s_part,        // [NCHUNK][256][10][16]
    int first)
{
    __shared__ float w_lds[CHUNK][WPC];          // 40 KB
    __shared__ float x_lds[CHUNK][DD][BTILE];    // 16 KB, d-major
    __shared__ float elg_lds[2][NT];             // 5 KB, double-buffered

    const int tid = threadIdx.x;
    const int o   = tid >> 6;        // wave id 0..9 (wave-uniform)
    const int bl  = tid & 63;
    const int b   = blockIdx.y * BTILE + bl;
    const int ijk0 = blockIdx.x * CHUNK;

    // ---- stage W chunk: CHUNK*1280 floats = 2560 float4, fully coalesced ----
    {
        const float4* wg = reinterpret_cast<const float4*>(W + (size_t)ijk0 * WPC);
        float4* wl = reinterpret_cast<float4*>(&w_lds[0][0]);
        #pragma unroll
        for (int i = 0; i < (CHUNK * WPC / 4) / NT; ++i)   // 4 iterations
            wl[tid + i * NT] = wg[tid + i * NT];
    }

    // ---- stage x: all CHUNK ijk tiles, coalesced float4, d-major ----
    {
        const float* xgrp = x + (size_t)(blockIdx.y * BTILE) * (IC * DD);
        #pragma unroll 1
        for (int i = tid; i < CHUNK * BTILE * 2; i += NT) {
            const int lq = i & 1;            // which half of the 8 d's
            const int lb = (i >> 1) & 63;    // batch within tile
            const int ls = i >> 7;           // ijk within chunk
            const float4 t = *reinterpret_cast<const float4*>(
                xgrp + (size_t)lb * (IC * DD) + (size_t)(ijk0 + ls) * DD + lq * 4);
            x_lds[ls][lq * 4 + 0][lb] = t.x;
            x_lds[ls][lq * 4 + 1][lb] = t.y;
            x_lds[ls][lq * 4 + 2][lb] = t.z;
            x_lds[ls][lq * 4 + 3][lb] = t.w;
        }
    }

    // per-thread copy of V[b,o,:] (registers; only routing passes need it)
    float vreg[EE];
    if (!first) {
        const float4* vp = reinterpret_cast<const float4*>(V + ((size_t)b * OO + o) * EE);
        #pragma unroll
        for (int q = 0; q < 4; ++q) {
            float4 t = vp[q];
            vreg[q * 4 + 0] = t.x; vreg[q * 4 + 1] = t.y;
            vreg[q * 4 + 2] = t.z; vreg[q * 4 + 3] = t.w;
        }
    }
    __syncthreads();

    float sacc[EE];
    #pragma unroll
    for (int e = 0; e < EE; ++e) sacc[e] = 0.f;

    int p = 0;
    #pragma unroll 1
    for (int s = 0; s < CHUNK; ++s) {
        // wave-uniform W slice for this (ijk, o): broadcast ds_read_b128
        const float4* wq = reinterpret_cast<const float4*>(&w_lds[s][o * (DD * EE)]);

        // u[e] = sum_d x_d * W[d][e]   (single W sweep, from LDS)
        float u[EE];
        #pragma unroll
        for (int e = 0; e < EE; ++e) u[e] = 0.f;
        #pragma unroll
        for (int d = 0; d < DD; ++d) {
            const float xv = x_lds[s][d][bl];    // 2 lanes/bank: free
            #pragma unroll
            for (int q = 0; q < 4; ++q) {
                const float4 w4 = wq[d * 4 + q]; // uniform addr -> broadcast
                u[q * 4 + 0] = fmaf(xv, w4.x, u[q * 4 + 0]);
                u[q * 4 + 1] = fmaf(xv, w4.y, u[q * 4 + 1]);
                u[q * 4 + 2] = fmaf(xv, w4.z, u[q * 4 + 2]);
                u[q * 4 + 3] = fmaf(xv, w4.w, u[q * 4 + 3]);
            }
        }

        float c;
        if (!first) {
            float lg = 0.f;
            #pragma unroll
            for (int e = 0; e < EE; ++e) lg = fmaf(u[e], vreg[e], lg);
            const float elg = __expf(lg);   // bounded logits: no max-sub
            elg_lds[p][tid] = elg;
            __syncthreads();                 // one barrier per ijk
            float den = 0.f;
            #pragma unroll
            for (int oo = 0; oo < OO; ++oo)
                den += elg_lds[p][oo * 64 + bl];   // 2 lanes/bank: free
            c = __fdividef(elg, den);
            p ^= 1;
        } else {
            c = 1.0f;   // uniform 0.1 folded into output mul
        }

        #pragma unroll
        for (int e = 0; e < EE; ++e)
            sacc[e] = fmaf(c, u[e], sacc[e]);
    }

    // write partial s for this chunk (first pass: c = 0.1 uniform, folded)
    const float mul = first ? 0.1f : 1.0f;
    float* sp = s_part + (((size_t)blockIdx.x * BATCH + b) * OO + o) * EE;
    #pragma unroll
    for (int q = 0; q < 4; ++q) {
        float4 t;
        t.x = mul * sacc[q * 4 + 0]; t.y = mul * sacc[q * 4 + 1];
        t.z = mul * sacc[q * 4 + 2]; t.w = mul * sacc[q * 4 + 3];
        reinterpret_cast<float4*>(sp)[q] = t;
    }
}

// squash kernel: reduce partial s over chunks, squash, update V (or write out).
// 4 waves/block split the 144-chunk reduction 4-way (36 chunks each), then
// LDS-reduce; wave 0 does the squash + store. 640 blocks keep it BW-bound.
__global__ __launch_bounds__(256) void caps_squash_kernel(
    const float* __restrict__ s_part,  // [NCHUNK][256][10][16]
    float* __restrict__ V,             // [256][10][16]
    float* __restrict__ out,           // [256][10][16]
    int accum, int last)
{
    __shared__ float red[3][64];
    const int lane = threadIdx.x & 63;
    const int w    = threadIdx.x >> 6;
    const int g    = blockIdx.x * 64 + lane;    // < 40960

    const float* sp = s_part + g;
    float s = 0.f;
    #pragma unroll 4
    for (int ch = w * (NCHUNK / 4); ch < (w + 1) * (NCHUNK / 4); ++ch)
        s += sp[(size_t)ch * (BATCH * OO * EE)];

    if (w > 0) red[w - 1][lane] = s;
    __syncthreads();
    if (w == 0) {
        s += red[0][lane] + red[1][lane] + red[2][lane];

        // squared norm over the 16-element e axis (lanes g..g+15 share (b,o))
        float sq = s * s;
        #pragma unroll
        for (int m = 1; m < 16; m <<= 1) sq += __shfl_xor(sq, m, 16);

        float scale = sq / (1.f + sq) / (sqrtf(sq) + 1e-6f);
        float v = scale * s;

        if (last)       out[g] = v;
        else if (accum) V[g]  += v;
        else            V[g]   = v;
    }
}

extern "C" void kernel_launch(void* const* d_in, const int* in_sizes, int n_in,
                              void* d_out, int out_size, void* d_ws, size_t ws_size,
                              hipStream_t stream) {
    const float* x = (const float*)d_in[0];   // [256,32,6,6,8]
    const float* W = (const float*)d_in[1];   // [1,32,6,6,10,8,16]
    float* out = (float*)d_out;               // [256,10,16]

    float* s_part = (float*)d_ws;                                   // NCHUNK*40960 floats
    float* V      = s_part + (size_t)NCHUNK * BATCH * OO * EE;      // 40960 floats

    dim3 grid(NCHUNK, NBT), blk(NT);
    const int sq_blocks = (BATCH * OO * EE) / 64;   // 640

    // iteration 1: b=0 -> c uniform 0.1; v1 -> V
    caps_pass_kernel<<<grid, blk, 0, stream>>>(x, W, V, s_part, 1);
    caps_squash_kernel<<<sq_blocks, 256, 0, stream>>>(s_part, V, out, 0, 0);
    // iteration 2: logits = dot(u_hat, v1); V += v2
    caps_pass_kernel<<<grid, blk, 0, stream>>>(x, W, V, s_part, 0);
    caps_squash_kernel<<<sq_blocks, 256, 0, stream>>>(s_part, V, out, 1, 0);
    // iteration 3 (final): logits = dot(u_hat, v1+v2); output v3
    caps_pass_kernel<<<grid, blk, 0, stream>>>(x, W, V, s_part, 0);
    caps_squash_kernel<<<sq_blocks, 256, 0, stream>>>(s_part, V, out, 0, 1);
}

// Round 10
// 150.708 us; speedup vs baseline: 1.2261x; 1.2261x over previous
//
#include <hip/hip_runtime.h>
#include <math.h>

// Problem constants
#define BATCH 256
#define IC    1152   // 32*6*6 input capsule positions
#define DD    8
#define OO    10
#define EE    16
#define BTILE 64     // batches per block (wave w owns rows 16w..16w+15)
#define NBT   4      // BATCH / BTILE
#define NT    256    // 4 waves
#define CHUNK 8      // ijk per block
#define NCHUNK 144   // IC / CHUNK

typedef __attribute__((ext_vector_type(8))) short short8;  // 8 bf16 (4 VGPR)
typedef __attribute__((ext_vector_type(4))) float f32x4;   // MFMA C/D

__device__ __forceinline__ unsigned short f2bf(float f) {  // RNE fp32->bf16
    unsigned u = __float_as_uint(f);
    unsigned r = u + 0x7FFFu + ((u >> 16) & 1u);
    return (unsigned short)(r >> 16);
}
__device__ __forceinline__ float bf2f(unsigned short h) {
    return __uint_as_float(((unsigned)h) << 16);
}

// MFMA pass kernel. Per (ijk,o): D[e][b] = W'[e][k].X'[k][b] with the bf16
// hi/lo split PACKED INTO K=32: lane-group g (k=8g..8g+7) supplies
// A={Wh,Wl,Wh,0}[g], B={Xh,Xh,Xl,0}[g], so ONE mfma_f32_16x16x32_bf16 gives
// Xh.Wh + Xh.Wl + Xl.Wh (error ~2^-18, fp32 accumulate).
// D layout (m89-verified): col=lane&15 = b, row=4*(lane>>4)+reg = e.
// -> logit sum over e = in-lane 4 FMA + shfl_xor(16)+shfl_xor(32);
//    softmax over o fully per-lane. NO barriers / NO LDS in the main loop.
// Per ijk per wave: 11 ds_read_b128 + 10 MFMA + ~150 VALU (vs r9's
// 32 b128 + ~1200 VALU scalar form at 43.5 us).
__global__ __launch_bounds__(NT) void caps_pass_kernel(
    const float* __restrict__ x,       // [256][1152][8]
    const float* __restrict__ W,       // [1152][10][8][16]
    const float* __restrict__ V,       // [256][10][16] accumulated v
    float* __restrict__ s_part,        // [NCHUNK][256][10][16]
    int first)
{
    // smem map (bytes): w_hi[8][160][8]bf16 @0 (20480), w_lo @20480,
    // x_hi[8][64][8] @40960 (8192), x_lo @49152, zpad @57344 (16).
    // Epilogue aliases [0,43008) as float sout[64][168] (W/x dead by then).
    __shared__ __align__(16) char smem[57360];
    unsigned short* w_hi = (unsigned short*)(smem);
    unsigned short* w_lo = (unsigned short*)(smem + 20480);
    unsigned short* x_hi = (unsigned short*)(smem + 40960);
    unsigned short* x_lo = (unsigned short*)(smem + 49152);
    unsigned short* zpad = (unsigned short*)(smem + 57344);

    const int tid  = threadIdx.x;
    const int wv   = tid >> 6;
    const int lane = tid & 63;
    const int q    = lane >> 4;    // k-group (0..3)
    const int em   = lane & 15;    // A-row (e) / B-col (b-local)
    const int ijk0 = blockIdx.x * CHUNK;
    const int bg0  = blockIdx.y * BTILE;

    if (tid < 4) ((unsigned*)zpad)[tid] = 0u;

    // ---- stage W chunk -> bf16 hi/lo, layout [s][o*16+e][d] (coalesced rd) ----
    {
        const float4* wg4 = reinterpret_cast<const float4*>(W + (size_t)ijk0 * (OO*DD*EE));
        #pragma unroll
        for (int i = 0; i < 10; ++i) {
            const int f = tid + i * NT;            // float4 unit, 0..2559
            const float4 t = wg4[f];
            const int l4 = f << 2;                 // element index
            const int e0 = l4 & 15;
            int rr = l4 >> 4;
            const int d = rr & 7; rr >>= 3;
            const int o = rr % 10, s = rr / 10;
            const float vv[4] = {t.x, t.y, t.z, t.w};
            #pragma unroll
            for (int j = 0; j < 4; ++j) {
                const unsigned short h = f2bf(vv[j]);
                const unsigned short l = f2bf(vv[j] - bf2f(h));
                const int off = (s*160 + o*16 + e0 + j) * 8 + d;
                w_hi[off] = h; w_lo[off] = l;
            }
        }
    }
    // ---- stage x chunk -> bf16 hi/lo, layout [s][b][d] ----
    {
        #pragma unroll
        for (int i = 0; i < 2; ++i) {
            const int u = tid + i * NT;            // 0..511 = (b,s)
            const int b = u >> 3, s = u & 7;
            const float* xp = x + ((size_t)(bg0 + b) * IC + (ijk0 + s)) * DD;
            const float4 xa = *reinterpret_cast<const float4*>(xp);
            const float4 xb = *reinterpret_cast<const float4*>(xp + 4);
            const float vv[8] = {xa.x,xa.y,xa.z,xa.w, xb.x,xb.y,xb.z,xb.w};
            short8 hv, lv;
            #pragma unroll
            for (int j = 0; j < 8; ++j) {
                const unsigned short h = f2bf(vv[j]);
                hv[j] = (short)h;
                lv[j] = (short)f2bf(vv[j] - bf2f(h));
            }
            const int off = (s*64 + b) * 8;
            *reinterpret_cast<short8*>(&x_hi[off]) = hv;
            *reinterpret_cast<short8*>(&x_lo[off]) = lv;
        }
    }

    // hoist v[b, o, e=4q..4q+3] into 10 float4 regs (routing passes only)
    f32x4 vreg[OO];
    if (!first) {
        const int bgl = bg0 + 16*wv + em;
        #pragma unroll
        for (int o = 0; o < OO; ++o) {
            const float4 t = *reinterpret_cast<const float4*>(
                V + (size_t)bgl * (OO*EE) + o*EE + 4*q);
            vreg[o] = (f32x4){t.x, t.y, t.z, t.w};
        }
    }

    __syncthreads();

    // per-lane operand bases: A(W): g0,g2->hi, g1->lo, g3->zero;
    //                         B(X): g0,g1->hi, g2->lo, g3->zero.
    const unsigned short* wbase = (q==1) ? w_lo : ((q==3) ? zpad : w_hi);
    const unsigned short* xbase = (q==2) ? x_lo : ((q==3) ? zpad : x_hi);
    const int msk = (q==3) ? 0 : 1;

    f32x4 sacc[OO];
    #pragma unroll
    for (int o = 0; o < OO; ++o) sacc[o] = (f32x4){0.f,0.f,0.f,0.f};

    #pragma unroll 1
    for (int s = 0; s < CHUNK; ++s) {
        const short8 xf = *reinterpret_cast<const short8*>(
            xbase + msk * ((s*64 + 16*wv + em) * 8));
        f32x4 u[OO];
        #pragma unroll
        for (int o = 0; o < OO; ++o) {
            const short8 wf = *reinterpret_cast<const short8*>(
                wbase + msk * ((s*160 + o*16 + em) * 8));
            u[o] = __builtin_amdgcn_mfma_f32_16x16x32_bf16(
                       wf, xf, (f32x4){0.f,0.f,0.f,0.f}, 0, 0, 0);
        }
        if (!first) {
            float elg[OO];
            float den = 0.f;
            #pragma unroll
            for (int o = 0; o < OO; ++o) {
                float t = u[o][0]*vreg[o][0] + u[o][1]*vreg[o][1]
                        + u[o][2]*vreg[o][2] + u[o][3]*vreg[o][3];
                t += __shfl_xor(t, 16);     // fold q-groups: full sum over e
                t += __shfl_xor(t, 32);
                elg[o] = __expf(t);         // bounded logits: no max-sub (r1-r9)
                den += elg[o];
            }
            const float rden = __fdividef(1.0f, den);
            #pragma unroll
            for (int o = 0; o < OO; ++o)
                sacc[o] += u[o] * (elg[o] * rden);
        } else {
            #pragma unroll
            for (int o = 0; o < OO; ++o) sacc[o] += u[o];
        }
    }

    // ---- epilogue: transpose through LDS (aliases W region) -> coalesced ----
    __syncthreads();
    float* sout = (float*)smem;            // [64][168] (pad: 4-way banks)
    const float mul = first ? 0.1f : 1.0f; // uniform c=0.1 folded here
    {
        const int bl = 16*wv + em;
        #pragma unroll
        for (int o = 0; o < OO; ++o)
            #pragma unroll
            for (int r = 0; r < 4; ++r)
                sout[bl*168 + o*16 + 4*q + r] = mul * sacc[o][r];
    }
    __syncthreads();
    {
        float* sp = s_part + ((size_t)blockIdx.x * BATCH + bg0) * (OO*EE);
        #pragma unroll
        for (int i = 0; i < 10; ++i) {
            const int f = tid + i*NT;       // float4 units over 64*160/4
            const int b = f / 40, c4 = (f % 40) * 4;
            const float4 t = *reinterpret_cast<const float4*>(&sout[b*168 + c4]);
            *reinterpret_cast<float4*>(&sp[(size_t)b*(OO*EE) + c4]) = t;
        }
    }
}

// squash kernel: reduce partial s over chunks, squash, update V (or write out).
__global__ __launch_bounds__(256) void caps_squash_kernel(
    const float* __restrict__ s_part,  // [NCHUNK][256][10][16]
    float* __restrict__ V,             // [256][10][16]
    float* __restrict__ out,           // [256][10][16]
    int accum, int last)
{
    __shared__ float red[3][64];
    const int lane = threadIdx.x & 63;
    const int w    = threadIdx.x >> 6;
    const int g    = blockIdx.x * 64 + lane;    // < 40960

    const float* sp = s_part + g;
    float s = 0.f;
    #pragma unroll 4
    for (int ch = w * (NCHUNK / 4); ch < (w + 1) * (NCHUNK / 4); ++ch)
        s += sp[(size_t)ch * (BATCH * OO * EE)];

    if (w > 0) red[w - 1][lane] = s;
    __syncthreads();
    if (w == 0) {
        s += red[0][lane] + red[1][lane] + red[2][lane];

        float sq = s * s;
        #pragma unroll
        for (int m = 1; m < 16; m <<= 1) sq += __shfl_xor(sq, m, 16);

        float scale = sq / (1.f + sq) / (sqrtf(sq) + 1e-6f);
        float v = scale * s;

        if (last)       out[g] = v;
        else if (accum) V[g]  += v;
        else            V[g]   = v;
    }
}

extern "C" void kernel_launch(void* const* d_in, const int* in_sizes, int n_in,
                              void* d_out, int out_size, void* d_ws, size_t ws_size,
                              hipStream_t stream) {
    const float* x = (const float*)d_in[0];   // [256,32,6,6,8]
    const float* W = (const float*)d_in[1];   // [1,32,6,6,10,8,16]
    float* out = (float*)d_out;               // [256,10,16]

    float* s_part = (float*)d_ws;                                   // NCHUNK*40960 floats
    float* V      = s_part + (size_t)NCHUNK * BATCH * OO * EE;      // 40960 floats

    dim3 grid(NCHUNK, NBT), blk(NT);
    const int sq_blocks = (BATCH * OO * EE) / 64;   // 640

    // iteration 1: b=0 -> c uniform 0.1; v1 -> V
    caps_pass_kernel<<<grid, blk, 0, stream>>>(x, W, V, s_part, 1);
    caps_squash_kernel<<<sq_blocks, 256, 0, stream>>>(s_part, V, out, 0, 0);
    // iteration 2: logits = dot(u_hat, v1); V += v2
    caps_pass_kernel<<<grid, blk, 0, stream>>>(x, W, V, s_part, 0);
    caps_squash_kernel<<<sq_blocks, 256, 0, stream>>>(s_part, V, out, 1, 0);
    // iteration 3 (final): logits = dot(u_hat, v1+v2); output v3
    caps_pass_kernel<<<grid, blk, 0, stream>>>(x, W, V, s_part, 0);
    caps_squash_kernel<<<sq_blocks, 256, 0, stream>>>(s_part, V, out, 0, 1);
}